// Round 5
// baseline (577.341 us; speedup 1.0000x reference)
//
#include <hip/hip_runtime.h>
#include <stdint.h>

// ---------------------------------------------------------------------------
// GIN (4 layers, CSR gather aggregation) + MLP classifier, bf16 MFMA GEMMs.
// R4 change: GEMM rewritten block-cooperative (v3).
//   Old: wave = 32 nodes x full M; re-read whole W strip from LDS per k-step
//   (16 ds_read_b128 vs 160cy MFMA -> LDS-bound), 64KiB LDS + 184 VGPR -> 2
//   blocks/CU, MfmaUtil 7%, latency-bound. New: block = 128 nodes x 128 ch,
//   waves split M (32ch/wave), W+X both LDS-staged (16+16 KiB, KS=64 slabs),
//   acc[8][2] (64 VGPR accs, ~110 total) -> 4 blocks/CU, 16 indep MFMA
//   chains/wave, wf reads amortized over 8 node-rows. M=256 via blockIdx.y.
// ---------------------------------------------------------------------------

#define NN  100000
#define EE  1600000
#define CIN 64
#define CC  128
#define NBK 782              // ceil(NN / 128) buckets, bucket = dst >> 7
#define CHUNK 8192           // edges per multi-split block
#define NCH 196              // ceil(EE / CHUNK)

typedef __attribute__((ext_vector_type(8))) __bf16 bf16x8;
typedef __attribute__((ext_vector_type(4))) float  f32x4;

__device__ __forceinline__ float bf2f(uint32_t u) { return __uint_as_float(u << 16); }
__device__ __forceinline__ ushort f2bf(float f) {          // RNE f32 -> bf16
  uint32_t u = __float_as_uint(f);
  u += 0x7fffu + ((u >> 16) & 1u);
  return (ushort)(u >> 16);
}

template<int ACT> __device__ __forceinline__ float actf(float z) {
  if constexpr (ACT == 1) return z >= 0.f ? z : 0.01f * z;       // lrelu
  else if constexpr (ACT == 2) return z >= 0.f ? z : 1e-4f * z;  // lrelu(lrelu)
  else return z;
}

// ---------------- multi-split CSR build ----------------
// pass 1: per-chunk histogram (LDS atomics) + bucket totals
__global__ __launch_bounds__(256) void ms_hist_kernel(const int* __restrict__ ei,
                                                      int* __restrict__ hist,
                                                      int* __restrict__ bh, int e) {
  __shared__ int h[NBK];
  for (int i = threadIdx.x; i < NBK; i += 256) h[i] = 0;
  __syncthreads();
  const int base = blockIdx.x * CHUNK;
  const int end = min(base + CHUNK, e);
  for (int i = base + threadIdx.x; i < end; i += 256)
    atomicAdd(&h[ei[e + i] >> 7], 1);
  __syncthreads();
  for (int i = threadIdx.x; i < NBK; i += 256) {
    hist[blockIdx.x * NBK + i] = h[i];
    if (h[i]) atomicAdd(&bh[i], h[i]);
  }
}

// one-block exclusive scan of NBK bucket counts -> boff[NBK+1]
__global__ __launch_bounds__(256) void bkt_scan_kernel(const int* __restrict__ bh,
                                                       int* __restrict__ boff, int e) {
  __shared__ int sd[256];
  int t = threadIdx.x;
  int base = t * 4;
  int v0 = base + 0 < NBK ? bh[base + 0] : 0;
  int v1 = base + 1 < NBK ? bh[base + 1] : 0;
  int v2 = base + 2 < NBK ? bh[base + 2] : 0;
  int v3 = base + 3 < NBK ? bh[base + 3] : 0;
  int ts = v0 + v1 + v2 + v3;
  sd[t] = ts; __syncthreads();
  for (int off = 1; off < 256; off <<= 1) {
    int u = (t >= off) ? sd[t - off] : 0;
    __syncthreads();
    sd[t] += u;
    __syncthreads();
  }
  int excl = sd[t] - ts;
  if (base + 0 < NBK) boff[base + 0] = excl;
  if (base + 1 < NBK) boff[base + 1] = excl + v0;
  if (base + 2 < NBK) boff[base + 2] = excl + v0 + v1;
  if (base + 3 < NBK) boff[base + 3] = excl + v0 + v1 + v2;
  if (t == 255) boff[NBK] = e;
}

// pass 2: turn hist[k][b] into chunk k's private start offset for bucket b
__global__ void ms_offs_kernel(int* __restrict__ hist, const int* __restrict__ boff) {
  int b = blockIdx.x * 256 + threadIdx.x;
  if (b >= NBK) return;
  int run = boff[b];
  for (int k = 0; k < NCH; ++k) {
    int t = hist[k * NBK + b];     // coalesced across b
    hist[k * NBK + b] = run;
    run += t;
  }
}

// pass 3: scatter into reserved ranges; LDS cursor atomics only
__global__ __launch_bounds__(256) void ms_scatter_kernel(const int* __restrict__ ei,
                                                         const int* __restrict__ hist,
                                                         uint* __restrict__ ebkt, int e) {
  __shared__ int cur[NBK];
  for (int i = threadIdx.x; i < NBK; i += 256) cur[i] = hist[blockIdx.x * NBK + i];
  __syncthreads();
  const int base = blockIdx.x * CHUNK;
  const int end = min(base + CHUNK, e);
  for (int i = base + threadIdx.x; i < end; i += 256) {
    int s = ei[i], d = ei[e + i];
    int p = atomicAdd(&cur[d >> 7], 1);
    ebkt[p] = ((uint)(d & 127) << 17) | (uint)s;
  }
}

// per-bucket node degrees via LDS counters (no global atomics)
__global__ __launch_bounds__(256) void bkt_deg_kernel(const uint* __restrict__ ebkt,
                                                      const int* __restrict__ boff,
                                                      int* __restrict__ deg, int n) {
  __shared__ int dl[128];
  int b = blockIdx.x;
  for (int i = threadIdx.x; i < 128; i += 256) dl[i] = 0;
  __syncthreads();
  int j1 = boff[b + 1];
  for (int j = boff[b] + threadIdx.x; j < j1; j += 256)
    atomicAdd(&dl[ebkt[j] >> 17], 1);
  __syncthreads();
  for (int i = threadIdx.x; i < 128; i += 256) {
    int node = (b << 7) + i;
    if (node < n) deg[node] = dl[i];
  }
}

// per-bucket CSR fill via LDS cursors; colb writes land in contiguous region
__global__ __launch_bounds__(256) void bkt_fill_kernel(const uint* __restrict__ ebkt,
                                                       const int* __restrict__ boff,
                                                       const int* __restrict__ rowp,
                                                       int* __restrict__ colb, int n) {
  __shared__ int cur[128];
  int b = blockIdx.x;
  for (int i = threadIdx.x; i < 128; i += 256) {
    int node = (b << 7) + i;
    cur[i] = (node < n) ? rowp[node] : 0;
  }
  __syncthreads();
  int j1 = boff[b + 1];
  for (int j = boff[b] + threadIdx.x; j < j1; j += 256) {
    uint v = ebkt[j];
    int p = atomicAdd(&cur[v >> 17], 1);
    colb[p] = (int)(v & 0x1FFFFu);
  }
}

// ---------------- node-degree scan (rowp) ----------------
__global__ void scan1_kernel(const int* __restrict__ deg, int* __restrict__ outp,
                             int* __restrict__ partial, int n) {
  __shared__ int sd[256];
  int t = threadIdx.x;
  int base = blockIdx.x * 1024 + t * 4;
  int v0 = base + 0 < n ? deg[base + 0] : 0;
  int v1 = base + 1 < n ? deg[base + 1] : 0;
  int v2 = base + 2 < n ? deg[base + 2] : 0;
  int v3 = base + 3 < n ? deg[base + 3] : 0;
  int ts = v0 + v1 + v2 + v3;
  sd[t] = ts; __syncthreads();
  for (int off = 1; off < 256; off <<= 1) {
    int u = (t >= off) ? sd[t - off] : 0;
    __syncthreads();
    sd[t] += u;
    __syncthreads();
  }
  int excl = sd[t] - ts;
  if (base + 0 < n) outp[base + 0] = excl;
  if (base + 1 < n) outp[base + 1] = excl + v0;
  if (base + 2 < n) outp[base + 2] = excl + v0 + v1;
  if (base + 3 < n) outp[base + 3] = excl + v0 + v1 + v2;
  if (t == 255) partial[blockIdx.x] = sd[255];
}

__global__ void scan2_kernel(int* __restrict__ partial, int nb) {
  __shared__ int sd[256];
  int t = threadIdx.x;
  int v = t < nb ? partial[t] : 0;
  sd[t] = v; __syncthreads();
  for (int off = 1; off < 256; off <<= 1) {
    int u = (t >= off) ? sd[t - off] : 0;
    __syncthreads();
    sd[t] += u;
    __syncthreads();
  }
  if (t < nb) partial[t] = sd[t] - v;  // exclusive block offsets
}

__global__ void scan3_kernel(int* __restrict__ rowp, const int* __restrict__ partial,
                             int n, int e) {
  int i = blockIdx.x * 256 + threadIdx.x;
  if (i == 0) rowp[n] = e;
  if (i < n) rowp[i] += partial[i >> 10];
}

// ---------------- prep ----------------
__global__ void bnprep_kernel(const float* b1, const float* g1, const float* be1,
                              const float* m1, const float* v1,
                              const float* bL, const float* gL, const float* beL,
                              const float* mL, const float* vL,
                              float* __restrict__ sc, float* __restrict__ tc) {
  int i = blockIdx.x * 256 + threadIdx.x;
  if (i >= 4 * 128) return;
  int layer = i >> 7, c = i & 127;
  float b, g, be, m, v;
  if (layer == 0) { b = b1[c]; g = g1[c]; be = be1[c]; m = m1[c]; v = v1[c]; }
  else { int o = (layer - 1) * 128 + c; b = bL[o]; g = gL[o]; be = beL[o]; m = mL[o]; v = vL[o]; }
  float s = g * rsqrtf(v + 1e-5f);
  sc[i] = s;
  tc[i] = (b - m) * s + be;
}

// transpose fp32 weights -> bf16 Wt (M x K row-major)
__global__ void wtprep_kernel(const float* __restrict__ W1, const float* __restrict__ WL,
                              const float* __restrict__ Wc1, const float* __restrict__ Wcl,
                              ushort* __restrict__ wt1, ushort* __restrict__ wtL,
                              ushort* __restrict__ wtc1, ushort* __restrict__ wtcl) {
  int i = blockIdx.x * 256 + threadIdx.x;
  if (i < 8192) {                                      // W1: 64x128 -> 128x64
    int m = i >> 6, k = i & 63;
    wt1[i] = f2bf(W1[k * 128 + m]);
  } else if (i < 8192 + 49152) {                       // WL: 3 x 128x128
    int j = i - 8192;
    int l = j >> 14, r = j & 16383, m = r >> 7, k = r & 127;
    wtL[j] = f2bf(WL[l * 16384 + k * 128 + m]);
  } else if (i < 8192 + 49152 + 32768) {               // Wc1: 128x256 -> 256x128
    int j = i - (8192 + 49152);
    int m = j >> 7, k = j & 127;
    wtc1[j] = f2bf(Wc1[k * 256 + m]);
  } else if (i < 8192 + 49152 + 32768 + 131072) {      // Wcl: 2 x 256x256
    int j = i - (8192 + 49152 + 32768);
    int l = j >> 16, r = j & 65535, m = r >> 8, k = r & 255;
    wtcl[j] = f2bf(Wcl[l * 65536 + k * 256 + m]);
  }
}

__global__ void xconv_kernel(const float* __restrict__ x, ushort* __restrict__ xb, int n4) {
  int i = blockIdx.x * 256 + threadIdx.x;
  if (i < n4) {
    float4 v = ((const float4*)x)[i];
    ushort4 o;
    o.x = f2bf(v.x); o.y = f2bf(v.y); o.z = f2bf(v.z); o.w = f2bf(v.w);
    ((ushort4*)xb)[i] = o;
  }
}

// ---------------- aggregation: zin = (1+eps)*h + sum_{j->i} h[j] ----------------
template<int C>
__global__ __launch_bounds__(256) void agg_kernel(
    const ushort* __restrict__ hb, const int* __restrict__ rowp,
    const int* __restrict__ colb, const float* __restrict__ ep,
    ushort* __restrict__ zout, int n)
{
  const int lane = threadIdx.x & 63;
  const int node = blockIdx.x * 4 + (threadIdx.x >> 6);
  if (node >= n) return;
  const float e1 = 1.0f + ep[0];
  int j0 = rowp[node], jend = rowp[node + 1];
  float a0 = 0.f, a1 = 0.f;
  for (; j0 < jend; j0 += 64) {
    int cnt = jend - j0; if (cnt > 64) cnt = 64;
    int myn = (lane < cnt) ? colb[j0 + lane] : 0;
    int jj = 0;
    for (; jj + 4 <= cnt; jj += 4) {
      int u0 = __shfl(myn, jj), u1 = __shfl(myn, jj + 1);
      int u2 = __shfl(myn, jj + 2), u3 = __shfl(myn, jj + 3);
      if (C == 128) {
        uint d0 = *(const uint*)(hb + (size_t)u0 * C + lane * 2);
        uint d1 = *(const uint*)(hb + (size_t)u1 * C + lane * 2);
        uint d2 = *(const uint*)(hb + (size_t)u2 * C + lane * 2);
        uint d3 = *(const uint*)(hb + (size_t)u3 * C + lane * 2);
        a0 += bf2f(d0 & 0xffff) + bf2f(d1 & 0xffff) + bf2f(d2 & 0xffff) + bf2f(d3 & 0xffff);
        a1 += bf2f(d0 >> 16) + bf2f(d1 >> 16) + bf2f(d2 >> 16) + bf2f(d3 >> 16);
      } else {
        a0 += bf2f(hb[(size_t)u0 * C + lane]) + bf2f(hb[(size_t)u1 * C + lane])
            + bf2f(hb[(size_t)u2 * C + lane]) + bf2f(hb[(size_t)u3 * C + lane]);
      }
    }
    for (; jj < cnt; ++jj) {
      int u = __shfl(myn, jj);
      if (C == 128) {
        uint d = *(const uint*)(hb + (size_t)u * C + lane * 2);
        a0 += bf2f(d & 0xffff); a1 += bf2f(d >> 16);
      } else {
        a0 += bf2f(hb[(size_t)u * C + lane]);
      }
    }
  }
  if (C == 128) {
    uint d = *(const uint*)(hb + (size_t)node * C + lane * 2);
    uint r = (uint)f2bf(e1 * bf2f(d & 0xffff) + a0)
           | ((uint)f2bf(e1 * bf2f(d >> 16) + a1) << 16);
    *(uint*)(zout + (size_t)node * C + lane * 2) = r;
  } else {
    zout[(size_t)node * C + lane] = f2bf(e1 * bf2f(hb[(size_t)node * C + lane]) + a0);
  }
}

// ---------------- GEMM v3: block = 128 nodes x 128 ch, waves split M --------
// hout[n][mB+c] = act( sum_k wt[mB+c][k]*xin[n][k] * sc + tc ); blockIdx.y = M chunk
template<int K, int M, int ACT, bool BN>
__global__ __launch_bounds__(256) void gemm_kernel(
    const ushort* __restrict__ xin,   // N x K  bf16
    const ushort* __restrict__ wt,    // M x K  bf16 (row-major)
    const float*  __restrict__ sc,    // M (BN scale) or unused
    const float*  __restrict__ tc,    // M (bias/shift)
    ushort* __restrict__ hout,        // N x M  bf16
    int n)
{
  constexpr int KS = 64;
  __shared__ ushort ldsW[128 * KS];   // 16 KiB, XOR-swizzled rows
  __shared__ ushort ldsX[128 * KS];   // 16 KiB, XOR-swizzled rows
  const int tid = threadIdx.x;
  const int wave = tid >> 6, lane = tid & 63;
  const int lr = lane & 15, lg = lane >> 4;
  const int n0 = blockIdx.x * 128;
  const int mB = blockIdx.y * 128;

  f32x4 acc[8][2];
  #pragma unroll
  for (int r = 0; r < 8; ++r) {
    acc[r][0] = (f32x4){0.f, 0.f, 0.f, 0.f};
    acc[r][1] = (f32x4){0.f, 0.f, 0.f, 0.f};
  }

  #pragma unroll
  for (int s = 0; s < K / KS; ++s) {
    if (s) __syncthreads();
    // stage W chunk: rows mB..mB+127, k slab s (128x64 bf16)
    #pragma unroll
    for (int c0 = 0; c0 < 1024; c0 += 256) {
      int c = c0 + tid;
      int m = c >> 3, kc = c & 7;
      uint4 v = *(const uint4*)(wt + (size_t)(mB + m) * K + s * KS + kc * 8);
      *(uint4*)((char*)ldsW + ((m * 128 + kc * 16) ^ ((m & 7) << 4))) = v;
    }
    // stage X tile: nodes n0..n0+127, k slab s
    #pragma unroll
    for (int c0 = 0; c0 < 1024; c0 += 256) {
      int c = c0 + tid;
      int r = c >> 3, kc = c & 7;
      int nd = n0 + r; if (nd >= n) nd = n - 1;
      uint4 v = *(const uint4*)(xin + (size_t)nd * K + s * KS + kc * 8);
      *(uint4*)((char*)ldsX + ((r * 128 + kc * 16) ^ ((r & 7) << 4))) = v;
    }
    __syncthreads();
    #pragma unroll
    for (int k0 = 0; k0 < KS; k0 += 32) {
      const int kb = (k0 + lg * 8) * 2;  // byte offset of this lane's 16B in a row
      bf16x8 wf0, wf1;
      {
        int m = wave * 32 + lr;
        wf0 = __builtin_bit_cast(bf16x8,
              *(const uint4*)((const char*)ldsW + ((m * 128 + kb) ^ ((m & 7) << 4))));
        m += 16;
        wf1 = __builtin_bit_cast(bf16x8,
              *(const uint4*)((const char*)ldsW + ((m * 128 + kb) ^ ((m & 7) << 4))));
      }
      #pragma unroll
      for (int r = 0; r < 8; ++r) {
        int xr = r * 16 + lr;
        bf16x8 xf = __builtin_bit_cast(bf16x8,
              *(const uint4*)((const char*)ldsX + ((xr * 128 + kb) ^ ((xr & 7) << 4))));
        acc[r][0] = __builtin_amdgcn_mfma_f32_16x16x32_bf16(wf0, xf, acc[r][0], 0, 0, 0);
        acc[r][1] = __builtin_amdgcn_mfma_f32_16x16x32_bf16(wf1, xf, acc[r][1], 0, 0, 0);
      }
    }
  }

  // epilogue: D col = node (lane&15), D rows = 4*lg + reg (consecutive channels)
  #pragma unroll
  for (int ct = 0; ct < 2; ++ct) {
    const int c0 = mB + wave * 32 + ct * 16 + lg * 4;
    float4 sv;
    if constexpr (BN) sv = *(const float4*)(sc + c0);
    else sv = make_float4(1.f, 1.f, 1.f, 1.f);
    const float4 tv = *(const float4*)(tc + c0);
    #pragma unroll
    for (int r = 0; r < 8; ++r) {
      const int node = n0 + r * 16 + lr;
      if (node < n) {
        const f32x4 a = acc[r][ct];
        ushort4 o;
        o.x = f2bf(actf<ACT>(a[0] * sv.x + tv.x));
        o.y = f2bf(actf<ACT>(a[1] * sv.y + tv.y));
        o.z = f2bf(actf<ACT>(a[2] * sv.z + tv.z));
        o.w = f2bf(actf<ACT>(a[3] * sv.w + tv.w));
        *(ushort4*)(hout + (size_t)node * M + c0) = o;
      }
    }
  }
}

// ---------------- final: sigmoid(s . Wf + bf) ----------------
__global__ __launch_bounds__(256) void final_kernel(
    const ushort* __restrict__ s, const float* __restrict__ wf,
    const float* __restrict__ bfp, float* __restrict__ out, int n)
{
  const int lane = threadIdx.x & 63;
  const int node = blockIdx.x * 4 + (threadIdx.x >> 6);
  if (node >= n) return;
  const uint2 d = *(const uint2*)(s + (size_t)node * 256 + lane * 4);
  const float4 w = *(const float4*)(wf + lane * 4);
  float acc = bf2f(d.x & 0xffff) * w.x + bf2f(d.x >> 16) * w.y
            + bf2f(d.y & 0xffff) * w.z + bf2f(d.y >> 16) * w.w;
  for (int off = 32; off; off >>= 1) acc += __shfl_down(acc, off);
  if (lane == 0) out[node] = 1.f / (1.f + expf(-(acc + bfp[0])));
}

// ---------------- launch ----------------
extern "C" void kernel_launch(void* const* d_in, const int* in_sizes, int n_in,
                              void* d_out, int out_size, void* d_ws, size_t ws_size,
                              hipStream_t stream)
{
  const float* x    = (const float*)d_in[0];
  const int*   ei   = (const int*)d_in[1];
  const float* eps1 = (const float*)d_in[3];
  const float* W1   = (const float*)d_in[4];
  const float* b1   = (const float*)d_in[5];
  const float* g1   = (const float*)d_in[6];
  const float* be1  = (const float*)d_in[7];
  const float* m1   = (const float*)d_in[8];
  const float* v1   = (const float*)d_in[9];
  const float* epsL = (const float*)d_in[10];
  const float* WL   = (const float*)d_in[11];
  const float* bL   = (const float*)d_in[12];
  const float* gL   = (const float*)d_in[13];
  const float* beL  = (const float*)d_in[14];
  const float* mL   = (const float*)d_in[15];
  const float* vL   = (const float*)d_in[16];
  const float* Wc1  = (const float*)d_in[17];
  const float* bc1  = (const float*)d_in[18];
  const float* Wcl  = (const float*)d_in[19];
  const float* bcl  = (const float*)d_in[20];
  const float* Wf   = (const float*)d_in[21];
  const float* bfp  = (const float*)d_in[22];
  float* out = (float*)d_out;

  char* w = (char*)d_ws;
  size_t off = 0;
  auto alloc = [&](size_t bytes) {
    char* p = w + off;
    off += (bytes + 255) & ~(size_t)255;
    return p;
  };
  ushort* bufA   = (ushort*)alloc((size_t)NN * 256 * 2);   // 51.2 MB
  ushort* bufB   = (ushort*)alloc((size_t)NN * 256 * 2);   // 51.2 MB
  int*    rowp   = (int*)alloc((NN + 1) * 4);
  int*    deg    = (int*)alloc(NN * 4);
  int*    colb   = (int*)alloc((size_t)EE * 4);
  uint*   ebkt   = (uint*)alloc((size_t)EE * 4);
  int*    hist   = (int*)alloc((size_t)NCH * NBK * 4);     // 613 KB
  int*    bh     = (int*)alloc(NBK * 4);
  int*    boff   = (int*)alloc((NBK + 1) * 4);
  int*    partial= (int*)alloc(1024);
  ushort* wt1    = (ushort*)alloc(8192 * 2);
  ushort* wtL    = (ushort*)alloc(49152 * 2);
  ushort* wtc1   = (ushort*)alloc(32768 * 2);
  ushort* wtcl   = (ushort*)alloc(131072 * 2);
  float*  sc     = (float*)alloc(512 * 4);
  float*  tc     = (float*)alloc(512 * 4);
  (void)ws_size; (void)in_sizes; (void)n_in; (void)out_size;

  // multi-split CSR build (by dst), no global atomics in the scatter
  hipMemsetAsync(bh, 0, NBK * 4, stream);
  ms_hist_kernel<<<NCH, 256, 0, stream>>>(ei, hist, bh, EE);
  bkt_scan_kernel<<<1, 256, 0, stream>>>(bh, boff, EE);
  ms_offs_kernel<<<(NBK + 255) / 256, 256, 0, stream>>>(hist, boff);
  ms_scatter_kernel<<<NCH, 256, 0, stream>>>(ei, hist, ebkt, EE);
  bkt_deg_kernel<<<NBK, 256, 0, stream>>>(ebkt, boff, deg, NN);
  scan1_kernel<<<98, 256, 0, stream>>>(deg, rowp, partial, NN);
  scan2_kernel<<<1, 256, 0, stream>>>(partial, 98);
  scan3_kernel<<<(NN + 255) / 256, 256, 0, stream>>>(rowp, partial, NN, EE);
  bkt_fill_kernel<<<NBK, 256, 0, stream>>>(ebkt, boff, rowp, colb, NN);

  // prep
  bnprep_kernel<<<2, 256, 0, stream>>>(b1, g1, be1, m1, v1, bL, gL, beL, mL, vL, sc, tc);
  wtprep_kernel<<<864, 256, 0, stream>>>(W1, WL, Wc1, Wcl, wt1, wtL, wtc1, wtcl);
  xconv_kernel<<<(NN * CIN / 4 + 255) / 256, 256, 0, stream>>>(x, bufA, NN * CIN / 4);

  const int GB = (NN + 127) / 128;   // 782 node-tiles

  // GIN layer 1 (64 -> 128), double lrelu
  agg_kernel<64><<<25000, 256, 0, stream>>>(bufA, rowp, colb, eps1, bufB, NN);
  gemm_kernel<64, 128, 2, true><<<dim3(GB, 1), 256, 0, stream>>>(bufB, wt1, sc, tc, bufA, NN);
  // GIN layers 2-4 (128 -> 128), double lrelu
  for (int i = 0; i < 3; ++i) {
    agg_kernel<128><<<25000, 256, 0, stream>>>(bufA, rowp, colb, epsL + i, bufB, NN);
    gemm_kernel<128, 128, 2, true><<<dim3(GB, 1), 256, 0, stream>>>(
        bufB, wtL + i * 16384, sc + 128 * (i + 1), tc + 128 * (i + 1), bufA, NN);
  }
  // classifier: 128 -> 256 (no act), 2 x (256 -> 256, lrelu), 256 -> 1 sigmoid
  gemm_kernel<128, 256, 0, false><<<dim3(GB, 2), 256, 0, stream>>>(bufA, wtc1, nullptr, bc1, bufB, NN);
  gemm_kernel<256, 256, 1, false><<<dim3(GB, 2), 256, 0, stream>>>(bufB, wtcl, nullptr, bcl, bufA, NN);
  gemm_kernel<256, 256, 1, false><<<dim3(GB, 2), 256, 0, stream>>>(bufA, wtcl + 65536, nullptr, bcl + 256, bufB, NN);
  final_kernel<<<25000, 256, 0, stream>>>(bufB, Wf, bfp, out, NN);
}

// Round 6
// 570.075 us; speedup vs baseline: 1.0127x; 1.0127x over previous
//
#include <hip/hip_runtime.h>
#include <stdint.h>

// ---------------------------------------------------------------------------
// GIN (4 layers, CSR gather aggregation) + MLP classifier, bf16 MFMA GEMMs.
// R5 change: agg_kernel v2 — wide-gather groups.
//   Old: per edge, whole wave loads 64 x dword (1 instr/edge, 4 edges in
//   flight) -> latency-bound (63us, 43% HBM, VALU 39%). New: 16-lane groups,
//   each lane global_load_dwordx4 (16B=8ch) -> 4 edges per load round (C=128;
//   8 for C=64), unroll 4 -> 16 edges / 4KB outstanding per wave. Group sums
//   combined via shfl_xor at the end. Same bytes, 4x fewer load instrs, 4x MLP.
// ---------------------------------------------------------------------------

#define NN  100000
#define EE  1600000
#define CIN 64
#define CC  128
#define NBK 782              // ceil(NN / 128) buckets, bucket = dst >> 7
#define CHUNK 8192           // edges per multi-split block
#define NCH 196              // ceil(EE / CHUNK)

typedef __attribute__((ext_vector_type(8))) __bf16 bf16x8;
typedef __attribute__((ext_vector_type(4))) float  f32x4;

__device__ __forceinline__ float bf2f(uint32_t u) { return __uint_as_float(u << 16); }
__device__ __forceinline__ float bf2f_hi(uint32_t u) { return __uint_as_float(u & 0xffff0000u); }
__device__ __forceinline__ ushort f2bf(float f) {          // RNE f32 -> bf16
  uint32_t u = __float_as_uint(f);
  u += 0x7fffu + ((u >> 16) & 1u);
  return (ushort)(u >> 16);
}

template<int ACT> __device__ __forceinline__ float actf(float z) {
  if constexpr (ACT == 1) return z >= 0.f ? z : 0.01f * z;       // lrelu
  else if constexpr (ACT == 2) return z >= 0.f ? z : 1e-4f * z;  // lrelu(lrelu)
  else return z;
}

// ---------------- multi-split CSR build ----------------
// pass 1: per-chunk histogram (LDS atomics) + bucket totals
__global__ __launch_bounds__(256) void ms_hist_kernel(const int* __restrict__ ei,
                                                      int* __restrict__ hist,
                                                      int* __restrict__ bh, int e) {
  __shared__ int h[NBK];
  for (int i = threadIdx.x; i < NBK; i += 256) h[i] = 0;
  __syncthreads();
  const int base = blockIdx.x * CHUNK;
  const int end = min(base + CHUNK, e);
  for (int i = base + threadIdx.x; i < end; i += 256)
    atomicAdd(&h[ei[e + i] >> 7], 1);
  __syncthreads();
  for (int i = threadIdx.x; i < NBK; i += 256) {
    hist[blockIdx.x * NBK + i] = h[i];
    if (h[i]) atomicAdd(&bh[i], h[i]);
  }
}

// one-block exclusive scan of NBK bucket counts -> boff[NBK+1]
__global__ __launch_bounds__(256) void bkt_scan_kernel(const int* __restrict__ bh,
                                                       int* __restrict__ boff, int e) {
  __shared__ int sd[256];
  int t = threadIdx.x;
  int base = t * 4;
  int v0 = base + 0 < NBK ? bh[base + 0] : 0;
  int v1 = base + 1 < NBK ? bh[base + 1] : 0;
  int v2 = base + 2 < NBK ? bh[base + 2] : 0;
  int v3 = base + 3 < NBK ? bh[base + 3] : 0;
  int ts = v0 + v1 + v2 + v3;
  sd[t] = ts; __syncthreads();
  for (int off = 1; off < 256; off <<= 1) {
    int u = (t >= off) ? sd[t - off] : 0;
    __syncthreads();
    sd[t] += u;
    __syncthreads();
  }
  int excl = sd[t] - ts;
  if (base + 0 < NBK) boff[base + 0] = excl;
  if (base + 1 < NBK) boff[base + 1] = excl + v0;
  if (base + 2 < NBK) boff[base + 2] = excl + v0 + v1;
  if (base + 3 < NBK) boff[base + 3] = excl + v0 + v1 + v2;
  if (t == 255) boff[NBK] = e;
}

// pass 2: turn hist[k][b] into chunk k's private start offset for bucket b
__global__ void ms_offs_kernel(int* __restrict__ hist, const int* __restrict__ boff) {
  int b = blockIdx.x * 256 + threadIdx.x;
  if (b >= NBK) return;
  int run = boff[b];
  for (int k = 0; k < NCH; ++k) {
    int t = hist[k * NBK + b];     // coalesced across b
    hist[k * NBK + b] = run;
    run += t;
  }
}

// pass 3: scatter into reserved ranges; LDS cursor atomics only
__global__ __launch_bounds__(256) void ms_scatter_kernel(const int* __restrict__ ei,
                                                         const int* __restrict__ hist,
                                                         uint* __restrict__ ebkt, int e) {
  __shared__ int cur[NBK];
  for (int i = threadIdx.x; i < NBK; i += 256) cur[i] = hist[blockIdx.x * NBK + i];
  __syncthreads();
  const int base = blockIdx.x * CHUNK;
  const int end = min(base + CHUNK, e);
  for (int i = base + threadIdx.x; i < end; i += 256) {
    int s = ei[i], d = ei[e + i];
    int p = atomicAdd(&cur[d >> 7], 1);
    ebkt[p] = ((uint)(d & 127) << 17) | (uint)s;
  }
}

// per-bucket node degrees via LDS counters (no global atomics)
__global__ __launch_bounds__(256) void bkt_deg_kernel(const uint* __restrict__ ebkt,
                                                      const int* __restrict__ boff,
                                                      int* __restrict__ deg, int n) {
  __shared__ int dl[128];
  int b = blockIdx.x;
  for (int i = threadIdx.x; i < 128; i += 256) dl[i] = 0;
  __syncthreads();
  int j1 = boff[b + 1];
  for (int j = boff[b] + threadIdx.x; j < j1; j += 256)
    atomicAdd(&dl[ebkt[j] >> 17], 1);
  __syncthreads();
  for (int i = threadIdx.x; i < 128; i += 256) {
    int node = (b << 7) + i;
    if (node < n) deg[node] = dl[i];
  }
}

// per-bucket CSR fill via LDS cursors; colb writes land in contiguous region
__global__ __launch_bounds__(256) void bkt_fill_kernel(const uint* __restrict__ ebkt,
                                                       const int* __restrict__ boff,
                                                       const int* __restrict__ rowp,
                                                       int* __restrict__ colb, int n) {
  __shared__ int cur[128];
  int b = blockIdx.x;
  for (int i = threadIdx.x; i < 128; i += 256) {
    int node = (b << 7) + i;
    cur[i] = (node < n) ? rowp[node] : 0;
  }
  __syncthreads();
  int j1 = boff[b + 1];
  for (int j = boff[b] + threadIdx.x; j < j1; j += 256) {
    uint v = ebkt[j];
    int p = atomicAdd(&cur[v >> 17], 1);
    colb[p] = (int)(v & 0x1FFFFu);
  }
}

// ---------------- node-degree scan (rowp) ----------------
__global__ void scan1_kernel(const int* __restrict__ deg, int* __restrict__ outp,
                             int* __restrict__ partial, int n) {
  __shared__ int sd[256];
  int t = threadIdx.x;
  int base = blockIdx.x * 1024 + t * 4;
  int v0 = base + 0 < n ? deg[base + 0] : 0;
  int v1 = base + 1 < n ? deg[base + 1] : 0;
  int v2 = base + 2 < n ? deg[base + 2] : 0;
  int v3 = base + 3 < n ? deg[base + 3] : 0;
  int ts = v0 + v1 + v2 + v3;
  sd[t] = ts; __syncthreads();
  for (int off = 1; off < 256; off <<= 1) {
    int u = (t >= off) ? sd[t - off] : 0;
    __syncthreads();
    sd[t] += u;
    __syncthreads();
  }
  int excl = sd[t] - ts;
  if (base + 0 < n) outp[base + 0] = excl;
  if (base + 1 < n) outp[base + 1] = excl + v0;
  if (base + 2 < n) outp[base + 2] = excl + v0 + v1;
  if (base + 3 < n) outp[base + 3] = excl + v0 + v1 + v2;
  if (t == 255) partial[blockIdx.x] = sd[255];
}

__global__ void scan2_kernel(int* __restrict__ partial, int nb) {
  __shared__ int sd[256];
  int t = threadIdx.x;
  int v = t < nb ? partial[t] : 0;
  sd[t] = v; __syncthreads();
  for (int off = 1; off < 256; off <<= 1) {
    int u = (t >= off) ? sd[t - off] : 0;
    __syncthreads();
    sd[t] += u;
    __syncthreads();
  }
  if (t < nb) partial[t] = sd[t] - v;  // exclusive block offsets
}

__global__ void scan3_kernel(int* __restrict__ rowp, const int* __restrict__ partial,
                             int n, int e) {
  int i = blockIdx.x * 256 + threadIdx.x;
  if (i == 0) rowp[n] = e;
  if (i < n) rowp[i] += partial[i >> 10];
}

// ---------------- prep ----------------
__global__ void bnprep_kernel(const float* b1, const float* g1, const float* be1,
                              const float* m1, const float* v1,
                              const float* bL, const float* gL, const float* beL,
                              const float* mL, const float* vL,
                              float* __restrict__ sc, float* __restrict__ tc) {
  int i = blockIdx.x * 256 + threadIdx.x;
  if (i >= 4 * 128) return;
  int layer = i >> 7, c = i & 127;
  float b, g, be, m, v;
  if (layer == 0) { b = b1[c]; g = g1[c]; be = be1[c]; m = m1[c]; v = v1[c]; }
  else { int o = (layer - 1) * 128 + c; b = bL[o]; g = gL[o]; be = beL[o]; m = mL[o]; v = vL[o]; }
  float s = g * rsqrtf(v + 1e-5f);
  sc[i] = s;
  tc[i] = (b - m) * s + be;
}

// transpose fp32 weights -> bf16 Wt (M x K row-major)
__global__ void wtprep_kernel(const float* __restrict__ W1, const float* __restrict__ WL,
                              const float* __restrict__ Wc1, const float* __restrict__ Wcl,
                              ushort* __restrict__ wt1, ushort* __restrict__ wtL,
                              ushort* __restrict__ wtc1, ushort* __restrict__ wtcl) {
  int i = blockIdx.x * 256 + threadIdx.x;
  if (i < 8192) {                                      // W1: 64x128 -> 128x64
    int m = i >> 6, k = i & 63;
    wt1[i] = f2bf(W1[k * 128 + m]);
  } else if (i < 8192 + 49152) {                       // WL: 3 x 128x128
    int j = i - 8192;
    int l = j >> 14, r = j & 16383, m = r >> 7, k = r & 127;
    wtL[j] = f2bf(WL[l * 16384 + k * 128 + m]);
  } else if (i < 8192 + 49152 + 32768) {               // Wc1: 128x256 -> 256x128
    int j = i - (8192 + 49152);
    int m = j >> 7, k = j & 127;
    wtc1[j] = f2bf(Wc1[k * 256 + m]);
  } else if (i < 8192 + 49152 + 32768 + 131072) {      // Wcl: 2 x 256x256
    int j = i - (8192 + 49152 + 32768);
    int l = j >> 16, r = j & 65535, m = r >> 8, k = r & 255;
    wtcl[j] = f2bf(Wcl[l * 65536 + k * 256 + m]);
  }
}

__global__ void xconv_kernel(const float* __restrict__ x, ushort* __restrict__ xb, int n4) {
  int i = blockIdx.x * 256 + threadIdx.x;
  if (i < n4) {
    float4 v = ((const float4*)x)[i];
    ushort4 o;
    o.x = f2bf(v.x); o.y = f2bf(v.y); o.z = f2bf(v.z); o.w = f2bf(v.w);
    ((ushort4*)xb)[i] = o;
  }
}

// ---------------- aggregation v2: zin = (1+eps)*h + sum_{j->i} h[j] -----------
// 16-lane groups (C=128) / 8-lane groups (C=64): lane loads dwordx4 (8 ch),
// 4 (or 8) edges per load round; partial sums combined across groups by
// shfl_xor; group 0 adds the (1+eps)*self term and writes 16B/lane.
template<int C>
__global__ __launch_bounds__(256) void agg_kernel(
    const ushort* __restrict__ hb, const int* __restrict__ rowp,
    const int* __restrict__ colb, const float* __restrict__ ep,
    ushort* __restrict__ zout, int n)
{
  constexpr int LPE = C / 8;     // lanes per edge (16 for C=128, 8 for C=64)
  constexpr int EPR = 64 / LPE;  // edges per round (4 or 8)
  const int lane = threadIdx.x & 63;
  const int node = blockIdx.x * 4 + (threadIdx.x >> 6);
  if (node >= n) return;
  const float e1 = 1.0f + ep[0];
  const int lo = lane & (LPE - 1);
  const int g  = lane / LPE;
  int j0 = rowp[node], jend = rowp[node + 1];

  float a0 = 0.f, a1 = 0.f, a2 = 0.f, a3 = 0.f,
        a4 = 0.f, a5 = 0.f, a6 = 0.f, a7 = 0.f;

  for (; j0 < jend; j0 += 64) {
    int cnt = jend - j0; if (cnt > 64) cnt = 64;
    int myn = (lane < cnt) ? colb[j0 + lane] : 0;
    int rounds = (cnt + EPR - 1) / EPR;
    #pragma unroll 4
    for (int r = 0; r < rounds; ++r) {
      int e = r * EPR + g;
      int u = __shfl(myn, e);          // all lanes active for the shuffle
      if (e < cnt) {
        const uint4 v = *(const uint4*)(hb + (size_t)u * C + lo * 8);
        a0 += bf2f(v.x); a1 += bf2f_hi(v.x);
        a2 += bf2f(v.y); a3 += bf2f_hi(v.y);
        a4 += bf2f(v.z); a5 += bf2f_hi(v.z);
        a6 += bf2f(v.w); a7 += bf2f_hi(v.w);
      }
    }
  }

  // combine group partials
  #pragma unroll
  for (int s = LPE; s < 64; s <<= 1) {
    a0 += __shfl_xor(a0, s); a1 += __shfl_xor(a1, s);
    a2 += __shfl_xor(a2, s); a3 += __shfl_xor(a3, s);
    a4 += __shfl_xor(a4, s); a5 += __shfl_xor(a5, s);
    a6 += __shfl_xor(a6, s); a7 += __shfl_xor(a7, s);
  }

  if (g == 0) {
    const uint4 d = *(const uint4*)(hb + (size_t)node * C + lo * 8);
    uint4 o;
    o.x = (uint)f2bf(e1 * bf2f(d.x) + a0) | ((uint)f2bf(e1 * bf2f_hi(d.x) + a1) << 16);
    o.y = (uint)f2bf(e1 * bf2f(d.y) + a2) | ((uint)f2bf(e1 * bf2f_hi(d.y) + a3) << 16);
    o.z = (uint)f2bf(e1 * bf2f(d.z) + a4) | ((uint)f2bf(e1 * bf2f_hi(d.z) + a5) << 16);
    o.w = (uint)f2bf(e1 * bf2f(d.w) + a6) | ((uint)f2bf(e1 * bf2f_hi(d.w) + a7) << 16);
    *(uint4*)(zout + (size_t)node * C + lo * 8) = o;
  }
}

// ---------------- GEMM v3: block = 128 nodes x 128 ch, waves split M --------
// hout[n][mB+c] = act( sum_k wt[mB+c][k]*xin[n][k] * sc + tc ); blockIdx.y = M chunk
template<int K, int M, int ACT, bool BN>
__global__ __launch_bounds__(256) void gemm_kernel(
    const ushort* __restrict__ xin,   // N x K  bf16
    const ushort* __restrict__ wt,    // M x K  bf16 (row-major)
    const float*  __restrict__ sc,    // M (BN scale) or unused
    const float*  __restrict__ tc,    // M (bias/shift)
    ushort* __restrict__ hout,        // N x M  bf16
    int n)
{
  constexpr int KS = 64;
  __shared__ ushort ldsW[128 * KS];   // 16 KiB, XOR-swizzled rows
  __shared__ ushort ldsX[128 * KS];   // 16 KiB, XOR-swizzled rows
  const int tid = threadIdx.x;
  const int wave = tid >> 6, lane = tid & 63;
  const int lr = lane & 15, lg = lane >> 4;
  const int n0 = blockIdx.x * 128;
  const int mB = blockIdx.y * 128;

  f32x4 acc[8][2];
  #pragma unroll
  for (int r = 0; r < 8; ++r) {
    acc[r][0] = (f32x4){0.f, 0.f, 0.f, 0.f};
    acc[r][1] = (f32x4){0.f, 0.f, 0.f, 0.f};
  }

  #pragma unroll
  for (int s = 0; s < K / KS; ++s) {
    if (s) __syncthreads();
    // stage W chunk: rows mB..mB+127, k slab s (128x64 bf16)
    #pragma unroll
    for (int c0 = 0; c0 < 1024; c0 += 256) {
      int c = c0 + tid;
      int m = c >> 3, kc = c & 7;
      uint4 v = *(const uint4*)(wt + (size_t)(mB + m) * K + s * KS + kc * 8);
      *(uint4*)((char*)ldsW + ((m * 128 + kc * 16) ^ ((m & 7) << 4))) = v;
    }
    // stage X tile: nodes n0..n0+127, k slab s
    #pragma unroll
    for (int c0 = 0; c0 < 1024; c0 += 256) {
      int c = c0 + tid;
      int r = c >> 3, kc = c & 7;
      int nd = n0 + r; if (nd >= n) nd = n - 1;
      uint4 v = *(const uint4*)(xin + (size_t)nd * K + s * KS + kc * 8);
      *(uint4*)((char*)ldsX + ((r * 128 + kc * 16) ^ ((r & 7) << 4))) = v;
    }
    __syncthreads();
    #pragma unroll
    for (int k0 = 0; k0 < KS; k0 += 32) {
      const int kb = (k0 + lg * 8) * 2;  // byte offset of this lane's 16B in a row
      bf16x8 wf0, wf1;
      {
        int m = wave * 32 + lr;
        wf0 = __builtin_bit_cast(bf16x8,
              *(const uint4*)((const char*)ldsW + ((m * 128 + kb) ^ ((m & 7) << 4))));
        m += 16;
        wf1 = __builtin_bit_cast(bf16x8,
              *(const uint4*)((const char*)ldsW + ((m * 128 + kb) ^ ((m & 7) << 4))));
      }
      #pragma unroll
      for (int r = 0; r < 8; ++r) {
        int xr = r * 16 + lr;
        bf16x8 xf = __builtin_bit_cast(bf16x8,
              *(const uint4*)((const char*)ldsX + ((xr * 128 + kb) ^ ((xr & 7) << 4))));
        acc[r][0] = __builtin_amdgcn_mfma_f32_16x16x32_bf16(wf0, xf, acc[r][0], 0, 0, 0);
        acc[r][1] = __builtin_amdgcn_mfma_f32_16x16x32_bf16(wf1, xf, acc[r][1], 0, 0, 0);
      }
    }
  }

  // epilogue: D col = node (lane&15), D rows = 4*lg + reg (consecutive channels)
  #pragma unroll
  for (int ct = 0; ct < 2; ++ct) {
    const int c0 = mB + wave * 32 + ct * 16 + lg * 4;
    float4 sv;
    if constexpr (BN) sv = *(const float4*)(sc + c0);
    else sv = make_float4(1.f, 1.f, 1.f, 1.f);
    const float4 tv = *(const float4*)(tc + c0);
    #pragma unroll
    for (int r = 0; r < 8; ++r) {
      const int node = n0 + r * 16 + lr;
      if (node < n) {
        const f32x4 a = acc[r][ct];
        ushort4 o;
        o.x = f2bf(actf<ACT>(a[0] * sv.x + tv.x));
        o.y = f2bf(actf<ACT>(a[1] * sv.y + tv.y));
        o.z = f2bf(actf<ACT>(a[2] * sv.z + tv.z));
        o.w = f2bf(actf<ACT>(a[3] * sv.w + tv.w));
        *(ushort4*)(hout + (size_t)node * M + c0) = o;
      }
    }
  }
}

// ---------------- final: sigmoid(s . Wf + bf) ----------------
__global__ __launch_bounds__(256) void final_kernel(
    const ushort* __restrict__ s, const float* __restrict__ wf,
    const float* __restrict__ bfp, float* __restrict__ out, int n)
{
  const int lane = threadIdx.x & 63;
  const int node = blockIdx.x * 4 + (threadIdx.x >> 6);
  if (node >= n) return;
  const uint2 d = *(const uint2*)(s + (size_t)node * 256 + lane * 4);
  const float4 w = *(const float4*)(wf + lane * 4);
  float acc = bf2f(d.x & 0xffff) * w.x + bf2f(d.x >> 16) * w.y
            + bf2f(d.y & 0xffff) * w.z + bf2f(d.y >> 16) * w.w;
  for (int off = 32; off; off >>= 1) acc += __shfl_down(acc, off);
  if (lane == 0) out[node] = 1.f / (1.f + expf(-(acc + bfp[0])));
}

// ---------------- launch ----------------
extern "C" void kernel_launch(void* const* d_in, const int* in_sizes, int n_in,
                              void* d_out, int out_size, void* d_ws, size_t ws_size,
                              hipStream_t stream)
{
  const float* x    = (const float*)d_in[0];
  const int*   ei   = (const int*)d_in[1];
  const float* eps1 = (const float*)d_in[3];
  const float* W1   = (const float*)d_in[4];
  const float* b1   = (const float*)d_in[5];
  const float* g1   = (const float*)d_in[6];
  const float* be1  = (const float*)d_in[7];
  const float* m1   = (const float*)d_in[8];
  const float* v1   = (const float*)d_in[9];
  const float* epsL = (const float*)d_in[10];
  const float* WL   = (const float*)d_in[11];
  const float* bL   = (const float*)d_in[12];
  const float* gL   = (const float*)d_in[13];
  const float* beL  = (const float*)d_in[14];
  const float* mL   = (const float*)d_in[15];
  const float* vL   = (const float*)d_in[16];
  const float* Wc1  = (const float*)d_in[17];
  const float* bc1  = (const float*)d_in[18];
  const float* Wcl  = (const float*)d_in[19];
  const float* bcl  = (const float*)d_in[20];
  const float* Wf   = (const float*)d_in[21];
  const float* bfp  = (const float*)d_in[22];
  float* out = (float*)d_out;

  char* w = (char*)d_ws;
  size_t off = 0;
  auto alloc = [&](size_t bytes) {
    char* p = w + off;
    off += (bytes + 255) & ~(size_t)255;
    return p;
  };
  ushort* bufA   = (ushort*)alloc((size_t)NN * 256 * 2);   // 51.2 MB
  ushort* bufB   = (ushort*)alloc((size_t)NN * 256 * 2);   // 51.2 MB
  int*    rowp   = (int*)alloc((NN + 1) * 4);
  int*    deg    = (int*)alloc(NN * 4);
  int*    colb   = (int*)alloc((size_t)EE * 4);
  uint*   ebkt   = (uint*)alloc((size_t)EE * 4);
  int*    hist   = (int*)alloc((size_t)NCH * NBK * 4);     // 613 KB
  int*    bh     = (int*)alloc(NBK * 4);
  int*    boff   = (int*)alloc((NBK + 1) * 4);
  int*    partial= (int*)alloc(1024);
  ushort* wt1    = (ushort*)alloc(8192 * 2);
  ushort* wtL    = (ushort*)alloc(49152 * 2);
  ushort* wtc1   = (ushort*)alloc(32768 * 2);
  ushort* wtcl   = (ushort*)alloc(131072 * 2);
  float*  sc     = (float*)alloc(512 * 4);
  float*  tc     = (float*)alloc(512 * 4);
  (void)ws_size; (void)in_sizes; (void)n_in; (void)out_size;

  // multi-split CSR build (by dst), no global atomics in the scatter
  hipMemsetAsync(bh, 0, NBK * 4, stream);
  ms_hist_kernel<<<NCH, 256, 0, stream>>>(ei, hist, bh, EE);
  bkt_scan_kernel<<<1, 256, 0, stream>>>(bh, boff, EE);
  ms_offs_kernel<<<(NBK + 255) / 256, 256, 0, stream>>>(hist, boff);
  ms_scatter_kernel<<<NCH, 256, 0, stream>>>(ei, hist, ebkt, EE);
  bkt_deg_kernel<<<NBK, 256, 0, stream>>>(ebkt, boff, deg, NN);
  scan1_kernel<<<98, 256, 0, stream>>>(deg, rowp, partial, NN);
  scan2_kernel<<<1, 256, 0, stream>>>(partial, 98);
  scan3_kernel<<<(NN + 255) / 256, 256, 0, stream>>>(rowp, partial, NN, EE);
  bkt_fill_kernel<<<NBK, 256, 0, stream>>>(ebkt, boff, rowp, colb, NN);

  // prep
  bnprep_kernel<<<2, 256, 0, stream>>>(b1, g1, be1, m1, v1, bL, gL, beL, mL, vL, sc, tc);
  wtprep_kernel<<<864, 256, 0, stream>>>(W1, WL, Wc1, Wcl, wt1, wtL, wtc1, wtcl);
  xconv_kernel<<<(NN * CIN / 4 + 255) / 256, 256, 0, stream>>>(x, bufA, NN * CIN / 4);

  const int GB = (NN + 127) / 128;   // 782 node-tiles

  // GIN layer 1 (64 -> 128), double lrelu
  agg_kernel<64><<<25000, 256, 0, stream>>>(bufA, rowp, colb, eps1, bufB, NN);
  gemm_kernel<64, 128, 2, true><<<dim3(GB, 1), 256, 0, stream>>>(bufB, wt1, sc, tc, bufA, NN);
  // GIN layers 2-4 (128 -> 128), double lrelu
  for (int i = 0; i < 3; ++i) {
    agg_kernel<128><<<25000, 256, 0, stream>>>(bufA, rowp, colb, epsL + i, bufB, NN);
    gemm_kernel<128, 128, 2, true><<<dim3(GB, 1), 256, 0, stream>>>(
        bufB, wtL + i * 16384, sc + 128 * (i + 1), tc + 128 * (i + 1), bufA, NN);
  }
  // classifier: 128 -> 256 (no act), 2 x (256 -> 256, lrelu), 256 -> 1 sigmoid
  gemm_kernel<128, 256, 0, false><<<dim3(GB, 2), 256, 0, stream>>>(bufA, wtc1, nullptr, bc1, bufB, NN);
  gemm_kernel<256, 256, 1, false><<<dim3(GB, 2), 256, 0, stream>>>(bufB, wtcl, nullptr, bcl, bufA, NN);
  gemm_kernel<256, 256, 1, false><<<dim3(GB, 2), 256, 0, stream>>>(bufA, wtcl + 65536, nullptr, bcl + 256, bufB, NN);
  final_kernel<<<25000, 256, 0, stream>>>(bufB, Wf, bfp, out, NN);
}